// Round 7
// baseline (254.803 us; speedup 1.0000x reference)
//
#include <hip/hip_runtime.h>
#include <cstdint>
#include <cstddef>

#define BB 256
#define TB 2048
#define NROWS (BB*TB)          // 524288 rows of [64]
#define R1 256                 // rows per k1 block
#define NBLK_K1 (NROWS/R1)     // 2048 blocks
#define NBLK1 4096             // partial granularity: 128-row groups (bit-compat R5/R6)

typedef float f32x4 __attribute__((ext_vector_type(4)));
typedef float f32x2 __attribute__((ext_vector_type(2)));

// ---- workspace layout (bytes) ----
#define OFF_X      0ull
#define SZ_X       ((size_t)NROWS*64*4)            // 128 MiB raw x_proj [bt][h]
#define OFF_PART   (OFF_X + SZ_X)
#define SZ_PART    ((size_t)128*NBLK1*4)           // 2 MiB partials [ch][4096]
#define OFF_STAT   (OFF_PART + SZ_PART)
#define SZ_STAT    (128*8)                         // f64 col sums / sumsq
#define OFF_PARAM  (OFF_STAT + SZ_STAT)            // scale[64] shift[64] thresh[1024]
#define SZ_PARAM   ((size_t)(64+64+1024)*4)
#define OFF_MASK   ((OFF_PARAM + SZ_PARAM + 255ull) & ~255ull)
#define SZ_MASK    ((size_t)NROWS*8)               // 4 MiB spike masks [b][t]

// ============ K1: x_proj = kin @ W^T + 128-row-granular col sum/sumsq ============
// A: global->register ring (8-lane broadcast, no LDS). W: LDS pair-interleaved
// so one b128 read = 2 cols x 2 c's, feeding v_pk_fma_f32 on f32x2 col-pair accs.
// Per-acc-element c-order remains 0..63 sequential -> bit-identical to R6.
__global__ __launch_bounds__(256, 2) void k1_gemm(const float* __restrict__ kin,
                                                  const float* __restrict__ Wsp,
                                                  float* __restrict__ xproj,
                                                  float* __restrict__ partials) {
  __shared__ f32x4 Wp[32 * 32];    // 16 KB: [pair p][cpair q ^ ((p>>2)&7)]
  __shared__ float Sm[64 * 33];    // 8.4 KB stat scratch
  __shared__ float Sq[64 * 33];    // 8.4 KB
  const int tid = threadIdx.x;
  const int ty = tid >> 3;         // 0..31 -> rows 8*ty..+7
  const int tx = tid & 7;          // col-pairs 4*tx..+3  (cols 8*tx..+7)
  const size_t r0 = (size_t)blockIdx.x * R1;

  // A prefetch ring: issue cc=0,1 groups before anything else
  const float* abase = kin + (r0 + 8 * (size_t)ty) * 64;
  f32x4 av[2][8];
  #pragma unroll
  for (int i = 0; i < 8; ++i)
    av[0][i] = __builtin_nontemporal_load((const f32x4*)(abase + i * 64 + 0));
  #pragma unroll
  for (int i = 0; i < 8; ++i)
    av[1][i] = __builtin_nontemporal_load((const f32x4*)(abase + i * 64 + 4));

  // stage W pair-interleaved: entry (p,q) = {W[2p][2q], W[2p+1][2q], W[2p][2q+1], W[2p+1][2q+1]}
  #pragma unroll
  for (int k = 0; k < 4; ++k) {
    int idx = k * 256 + tid;             // 0..1023
    int p = idx >> 5, q = idx & 31;
    float2 w0 = *(const float2*)(Wsp + (2 * p) * 64 + 2 * q);
    float2 w1 = *(const float2*)(Wsp + (2 * p + 1) * 64 + 2 * q);
    Wp[p * 32 + (q ^ ((p >> 2) & 7))] = (f32x4){w0.x, w1.x, w0.y, w1.y};
  }
  __syncthreads();

  f32x2 acc2[8][4];
  #pragma unroll
  for (int i = 0; i < 8; ++i)
    #pragma unroll
    for (int jp = 0; jp < 4; ++jp) acc2[i][jp] = (f32x2){0.f, 0.f};

  #pragma unroll
  for (int cc = 0; cc < 16; ++cc) {
    const int buf = cc & 1;
    f32x4 q0[4], q1[4];
    #pragma unroll
    for (int jp = 0; jp < 4; ++jp) {
      const int p = 4 * tx + jp;
      q0[jp] = Wp[p * 32 + ((2 * cc)     ^ tx)];   // c = 4cc, 4cc+1
      q1[jp] = Wp[p * 32 + ((2 * cc + 1) ^ tx)];   // c = 4cc+2, 4cc+3
    }
    #pragma unroll
    for (int i = 0; i < 8; ++i) {
      f32x4 a = av[buf][i];
      #pragma unroll
      for (int jp = 0; jp < 4; ++jp) {
        acc2[i][jp] = __builtin_elementwise_fma((f32x2){a.x, a.x}, q0[jp].xy, acc2[i][jp]);
        acc2[i][jp] = __builtin_elementwise_fma((f32x2){a.y, a.y}, q0[jp].zw, acc2[i][jp]);
        acc2[i][jp] = __builtin_elementwise_fma((f32x2){a.z, a.z}, q1[jp].xy, acc2[i][jp]);
        acc2[i][jp] = __builtin_elementwise_fma((f32x2){a.w, a.w}, q1[jp].zw, acc2[i][jp]);
      }
    }
    if (cc < 14) {
      #pragma unroll
      for (int i = 0; i < 8; ++i)
        av[buf][i] = __builtin_nontemporal_load((const f32x4*)(abase + i * 64 + (cc + 2) * 4));
    }
  }

  #pragma unroll
  for (int i = 0; i < 8; ++i) {
    const size_t row = r0 + 8 * ty + i;
    f32x4 lo = {acc2[i][0].x, acc2[i][0].y, acc2[i][1].x, acc2[i][1].y};
    f32x4 hi = {acc2[i][2].x, acc2[i][2].y, acc2[i][3].x, acc2[i][3].y};
    *(f32x4*)(xproj + row * 64 + 8 * tx)     = lo;
    *(f32x4*)(xproj + row * 64 + 8 * tx + 4) = hi;
  }

  // stats: identical value ordering to R6 (i ascending within 8-row group)
  #pragma unroll
  for (int j = 0; j < 8; ++j) {
    const int col = 8 * tx + j;
    float s = 0.f, q = 0.f;
    #pragma unroll
    for (int i = 0; i < 8; ++i) {
      float v = (j & 1) ? acc2[i][j >> 1].y : acc2[i][j >> 1].x;
      s += v;
      q += v * v;
    }
    Sm[col * 33 + ty] = s;
    Sq[col * 33 + ty] = q;
  }
  __syncthreads();
  if (tid < 64) {
    float s0 = 0.f, q0 = 0.f, s1 = 0.f, q1 = 0.f;
    #pragma unroll
    for (int g = 0; g < 16; ++g)  { s0 += Sm[tid * 33 + g]; q0 += Sq[tid * 33 + g]; }
    #pragma unroll
    for (int g = 16; g < 32; ++g) { s1 += Sm[tid * 33 + g]; q1 += Sq[tid * 33 + g]; }
    const size_t p0 = 2 * (size_t)blockIdx.x;
    partials[(size_t)tid * NBLK1 + p0]            = s0;
    partials[(size_t)tid * NBLK1 + p0 + 1]        = s1;
    partials[(size_t)(64 + tid) * NBLK1 + p0]     = q0;
    partials[(size_t)(64 + tid) * NBLK1 + p0 + 1] = q1;
  }
}

// ============ K2a: deterministic f64 reduction (coalesced rows) ============
__global__ __launch_bounds__(256) void k2a_reduce(const float* __restrict__ partials,
                                                  double* __restrict__ statd) {
  __shared__ double sd[256];
  const int idx = blockIdx.x;              // 0..127
  double acc = 0.0;
  for (int k = threadIdx.x; k < NBLK1; k += 256)
    acc += (double)partials[(size_t)idx * NBLK1 + k];
  sd[threadIdx.x] = acc;
  __syncthreads();
  for (int s = 128; s > 0; s >>= 1) {
    if (threadIdx.x < s) sd[threadIdx.x] += sd[threadIdx.x + s];
    __syncthreads();
  }
  if (threadIdx.x == 0) statd[idx] = sd[0];
}

// ============ K2b: BN scale/shift + dynamic thresholds (parallel, 5 blocks) ============
__global__ __launch_bounds__(256) void k2b_final(const double* __restrict__ statd,
                                                 const float* __restrict__ gamma,
                                                 const float* __restrict__ beta,
                                                 const float* __restrict__ tda,
                                                 const float* __restrict__ Wtda,
                                                 const float* __restrict__ btda,
                                                 float* __restrict__ param) {
  const int tid = threadIdx.x, blk = blockIdx.x;
  if (blk == 4) {
    if (tid < 64) {
      double mean = statd[tid] / (double)NROWS;
      double ex2  = statd[64 + tid] / (double)NROWS;
      double var  = ex2 - mean * mean;
      double sc   = (double)gamma[tid] / sqrt(var + 1e-5);
      param[tid]      = (float)sc;
      param[64 + tid] = (float)((double)beta[tid] - mean * sc);
    }
    return;
  }
  const int g = blk * 256 + tid;           // 0..1023 = b*4 + j
  const int b = g >> 2, j = g & 3;
  double acc = (double)btda[j];
  for (int k = 0; k < 50; ++k)
    acc += (double)tda[b * 50 + k] * (double)Wtda[j * 50 + k];
  double sig = 1.0 / (1.0 + exp(-acc));
  param[128 + g] = (float)(1.0 + 0.5 * sig);
}

// ============ K3: layer-1 LIF scan, wave per b, lane = channel h ============
#define K3_LOAD(BUF, TBASE)                         \
  { _Pragma("unroll") for (int i_ = 0; i_ < 64; ++i_) \
      BUF[i_] = xr[(size_t)((TBASE) + i_) * 64]; }

#define K3_CHUNK(CUR, NXT0, TBASE)                                   \
  { unsigned long long keep = 0;                                     \
    _Pragma("unroll") for (int i_ = 0; i_ < 64; ++i_) {              \
      bool sp = (mem >= 1.0f);                                       \
      unsigned long long mb = __ballot(sp);                          \
      if (h == i_) keep = mb;                                        \
      float xrn = (i_ < 63) ? CUR[(i_ + 1) & 63] : (NXT0);           \
      float xn = fmaf(xrn, sc, sh);                                  \
      mem = sp ? xn : fmaf(mem, 0.9f, xn);                           \
    }                                                                \
    masksB[(size_t)b * TB + (TBASE) + h] = keep; }

__global__ __launch_bounds__(64) void k3_scan1(const float* __restrict__ xproj,
                                               const float* __restrict__ param,
                                               unsigned long long* __restrict__ masksB) {
  const int b = blockIdx.x, h = threadIdx.x;
  const float sc = param[h], sh = param[64 + h];
  const float* xr = xproj + (size_t)b * TB * 64 + h;
  float xa[64], xb[64];

  K3_LOAD(xa, 0)
  float mem = fmaf(xa[0], sc, sh);   // t=0 post-add state

  #pragma unroll 1
  for (int t0 = 0; t0 < TB; t0 += 128) {
    K3_LOAD(xb, t0 + 64)
    K3_CHUNK(xa, xb[0], t0)
    if (t0 + 128 < TB) { K3_LOAD(xa, t0 + 128) }
    K3_CHUNK(xb, xa[0], t0 + 64)    // final chunk: trailing xa[0] is dead
  }
}

// ============ K45: fused cur2 (into LDS) + layer-2 LIF scan, block per b ============
#define K45_LOAD(BUF, TBASE)                                             \
  { _Pragma("unroll") for (int k_ = 0; k_ < 16; ++k_) {                  \
      f32x4 v = *(const f32x4*)(cr + (TBASE) + 4 * k_);                  \
      BUF[4 * k_] = v.x; BUF[4 * k_ + 1] = v.y;                          \
      BUF[4 * k_ + 2] = v.z; BUF[4 * k_ + 3] = v.w; } }

#define K45_CHUNK(CUR, NXT0)                                  \
  { _Pragma("unroll") for (int i_ = 0; i_ < 64; ++i_) {       \
      bool sp = (mem >= th);                                  \
      cnt += sp ? 1u : 0u;                                    \
      float xn = (i_ < 63) ? CUR[(i_ + 1) & 63] : (NXT0);     \
      mem = sp ? xn : fmaf(mem, 0.9f, xn);                    \
    } }

__global__ __launch_bounds__(256) void k45_cur2scan(const unsigned long long* __restrict__ masksB,
                                                    const float* __restrict__ Wc,
                                                    const float* __restrict__ lat,
                                                    const float* __restrict__ param,
                                                    float* __restrict__ out) {
  __shared__ float WcL[256];
  __shared__ float latL[16];
  __shared__ float lbuf[4][TB + 4];     // padded rows (stride 2052 floats)
  const int tid = threadIdx.x, b = blockIdx.x;
  WcL[tid] = Wc[tid];
  if (tid < 16) latL[tid] = lat[tid];
  __syncthreads();

  // phase 1: cur2 for all t (identical math to old k4), into LDS
  #pragma unroll 1
  for (int c = 0; c < 8; ++c) {
    const int t = c * 256 + tid;
    const unsigned long long m = masksB[(size_t)b * TB + t];
    const unsigned lo = (unsigned)m, hi = (unsigned)(m >> 32);
    float v0 = 0.f, v1 = 0.f, v2 = 0.f, v3 = 0.f;
    #pragma unroll
    for (int hh = 0; hh < 32; ++hh) {
      const float bit = (float)((lo >> hh) & 1u);
      v0 = fmaf(bit, WcL[hh],       v0);
      v1 = fmaf(bit, WcL[64 + hh],  v1);
      v2 = fmaf(bit, WcL[128 + hh], v2);
      v3 = fmaf(bit, WcL[192 + hh], v3);
    }
    #pragma unroll
    for (int hh = 32; hh < 64; ++hh) {
      const float bit = (float)((hi >> (hh - 32)) & 1u);
      v0 = fmaf(bit, WcL[hh],       v0);
      v1 = fmaf(bit, WcL[64 + hh],  v1);
      v2 = fmaf(bit, WcL[128 + hh], v2);
      v3 = fmaf(bit, WcL[192 + hh], v3);
    }
    { float cx = v0 * latL[0];  cx = fmaf(v1, latL[4],  cx); cx = fmaf(v2, latL[8],  cx); cx = fmaf(v3, latL[12], cx); lbuf[0][t] = cx; }
    { float cx = v0 * latL[1];  cx = fmaf(v1, latL[5],  cx); cx = fmaf(v2, latL[9],  cx); cx = fmaf(v3, latL[13], cx); lbuf[1][t] = cx; }
    { float cx = v0 * latL[2];  cx = fmaf(v1, latL[6],  cx); cx = fmaf(v2, latL[10], cx); cx = fmaf(v3, latL[14], cx); lbuf[2][t] = cx; }
    { float cx = v0 * latL[3];  cx = fmaf(v1, latL[7],  cx); cx = fmaf(v2, latL[11], cx); cx = fmaf(v3, latL[15], cx); lbuf[3][t] = cx; }
  }
  __syncthreads();
  if (tid >= 64) return;

  // phase 2: wave 0 scans from LDS; lanes mirror 4 chains (identical math to old k5)
  const int j4 = tid & 3;
  const float th = param[128 + b * 4 + j4];
  const float* cr = lbuf[j4];
  float ca[64], cb[64];

  K45_LOAD(ca, 0)
  float mem = ca[0];
  unsigned cnt = 0;

  #pragma unroll 1
  for (int t0 = 0; t0 < TB; t0 += 128) {
    K45_LOAD(cb, t0 + 64)
    K45_CHUNK(ca, cb[0])
    if (t0 + 128 < TB) { K45_LOAD(ca, t0 + 128) }
    K45_CHUNK(cb, ca[0])
  }
  if (tid < 4) out[b * 4 + j4] = (float)cnt;
}

extern "C" void kernel_launch(void* const* d_in, const int* in_sizes, int n_in,
                              void* d_out, int out_size, void* d_ws, size_t ws_size,
                              hipStream_t stream) {
  const float* kin   = (const float*)d_in[0];
  const float* tda   = (const float*)d_in[1];
  const float* Wsp   = (const float*)d_in[2];
  const float* gamma = (const float*)d_in[3];
  const float* beta  = (const float*)d_in[4];
  const float* Wc    = (const float*)d_in[5];
  const float* lat   = (const float*)d_in[6];
  const float* Wtda  = (const float*)d_in[7];
  const float* btda  = (const float*)d_in[8];

  char* ws = (char*)d_ws;
  float*  xproj    = (float*)(ws + OFF_X);
  float*  partials = (float*)(ws + OFF_PART);
  double* statd    = (double*)(ws + OFF_STAT);
  float*  param    = (float*)(ws + OFF_PARAM);
  unsigned long long* masksB = (unsigned long long*)(ws + OFF_MASK);
  float*  out      = (float*)d_out;

  k1_gemm  <<<dim3(NBLK_K1), dim3(256), 0, stream>>>(kin, Wsp, xproj, partials);
  k2a_reduce<<<dim3(128),  dim3(256), 0, stream>>>(partials, statd);
  k2b_final<<<dim3(5),     dim3(256), 0, stream>>>(statd, gamma, beta, tda, Wtda, btda, param);
  k3_scan1 <<<dim3(BB),    dim3(64),  0, stream>>>(xproj, param, masksB);
  k45_cur2scan<<<dim3(BB), dim3(256), 0, stream>>>(masksB, Wc, lat, param, out);
}

// Round 8
// 158.228 us; speedup vs baseline: 1.6104x; 1.6104x over previous
//
#include <hip/hip_runtime.h>
#include <cstdint>
#include <cstddef>

#define BB 256
#define TB 2048
#define NROWS (BB*TB)          // 524288 rows of [64]
#define R1 256                 // rows per k1 block
#define NBLK_K1 (NROWS/R1)     // 2048 blocks
#define NBLK1 4096             // partial granularity: 128-row groups (bit-compat R5/R6)

typedef float f32x4 __attribute__((ext_vector_type(4)));

// ---- workspace layout (bytes) ----
#define OFF_X      0ull
#define SZ_X       ((size_t)NROWS*64*4)            // 128 MiB raw x_proj [bt][h]
#define OFF_PART   (OFF_X + SZ_X)
#define SZ_PART    ((size_t)128*NBLK1*4)           // 2 MiB partials [ch][4096]
#define OFF_STAT   (OFF_PART + SZ_PART)
#define SZ_STAT    (128*8)                         // f64 col sums / sumsq
#define OFF_PARAM  (OFF_STAT + SZ_STAT)            // scale[64] shift[64] thresh[1024]
#define SZ_PARAM   ((size_t)(64+64+1024)*4)
#define OFF_MASK   ((OFF_PARAM + SZ_PARAM + 255ull) & ~255ull)
#define SZ_MASK    ((size_t)NROWS*8)               // 4 MiB spike masks [b][t]

// async global->LDS, 16 B per lane
__device__ __forceinline__ void gll16(const float* g, void* l) {
  __builtin_amdgcn_global_load_lds(
      (const __attribute__((address_space(1))) unsigned int*)g,
      (__attribute__((address_space(3))) unsigned int*)l, 16, 0, 0);
}

// ============ K1: x_proj = kin @ W^T + 128-row-granular col sum/sumsq ============
// 256 rows x 256 threads, 8x8 tile (bit-identical FMA order to R6).
// A staged via global_load_lds into two half-K buffers (linear LDS dest,
// XOR swizzle applied on the global source chunk index); A1 flies under half-0 compute.
__global__ __launch_bounds__(256, 2) void k1_gemm(const float* __restrict__ kin,
                                                  const float* __restrict__ Wsp,
                                                  float* __restrict__ xproj,
                                                  float* __restrict__ partials) {
  __shared__ float4 A0[R1 * 8];    // 32 KB: [r][q ^ ((r>>3)&7)], c 0..31
  __shared__ float4 A1[R1 * 8];    // 32 KB: c 32..63
  __shared__ float4 Ws4[64 * 16];  // 16 KB: [h][cc ^ ((h>>3)&7)]
  const int tid = threadIdx.x;
  const int ty = tid >> 3;         // 0..31 -> rows 8*ty..+7
  const int tx = tid & 7;          // cols 8*tx..+7
  const size_t r0 = (size_t)blockIdx.x * R1;
  const float* gA = kin + r0 * 64;

  // ---- issue A0 stage (async): slot idx -> row r=idx>>3, lds q=idx&7,
  //      global chunk gq = q ^ ((r>>3)&7)  (inverse of read-side swizzle)
  #pragma unroll
  for (int k = 0; k < 8; ++k) {
    const int idx = k * 256 + tid;
    const int r = idx >> 3, q = idx & 7;
    const int gq = q ^ ((r >> 3) & 7);
    gll16(gA + (size_t)r * 64 + gq * 4, &A0[idx]);
  }
  // ---- stage W (16 KB, once) via regular loads
  const float4* W4 = (const float4*)Wsp;
  #pragma unroll
  for (int k = 0; k < 4; ++k) {
    int idx = k * 256 + tid;
    int h = idx >> 4, cc = idx & 15;
    Ws4[h * 16 + (cc ^ ((h >> 3) & 7))] = W4[idx];
  }
  __syncthreads();                 // A0 + W resident

  // ---- issue A1 stage (async) -> flies under half-0 compute
  #pragma unroll
  for (int k = 0; k < 8; ++k) {
    const int idx = k * 256 + tid;
    const int r = idx >> 3, q = idx & 7;
    const int gq = 8 + (q ^ ((r >> 3) & 7));
    gll16(gA + (size_t)r * 64 + gq * 4, &A1[idx]);
  }

  float acc[8][8];
  #pragma unroll
  for (int i = 0; i < 8; ++i)
    #pragma unroll
    for (int j = 0; j < 8; ++j) acc[i][j] = 0.f;

  // ---- half 0: cc = 0..7 (c = 0..31)
  #pragma unroll 1
  for (int cc = 0; cc < 8; ++cc) {
    float4 av[8], wv[8];
    #pragma unroll
    for (int i = 0; i < 8; ++i)
      av[i] = A0[(8 * ty + i) * 8 + (cc ^ (ty & 7))];
    #pragma unroll
    for (int j = 0; j < 8; ++j)
      wv[j] = Ws4[(8 * tx + j) * 16 + (cc ^ tx)];
    #pragma unroll
    for (int i = 0; i < 8; ++i)
      #pragma unroll
      for (int j = 0; j < 8; ++j) {
        acc[i][j] = fmaf(av[i].x, wv[j].x, acc[i][j]);
        acc[i][j] = fmaf(av[i].y, wv[j].y, acc[i][j]);
        acc[i][j] = fmaf(av[i].z, wv[j].z, acc[i][j]);
        acc[i][j] = fmaf(av[i].w, wv[j].w, acc[i][j]);
      }
  }
  __syncthreads();                 // drains A1 loads (vmcnt) + wave sync

  // ---- half 1: cc = 8..15 (c = 32..63)
  #pragma unroll 1
  for (int cc = 8; cc < 16; ++cc) {
    float4 av[8], wv[8];
    #pragma unroll
    for (int i = 0; i < 8; ++i)
      av[i] = A1[(8 * ty + i) * 8 + ((cc - 8) ^ (ty & 7))];
    #pragma unroll
    for (int j = 0; j < 8; ++j)
      wv[j] = Ws4[(8 * tx + j) * 16 + (cc ^ tx)];
    #pragma unroll
    for (int i = 0; i < 8; ++i)
      #pragma unroll
      for (int j = 0; j < 8; ++j) {
        acc[i][j] = fmaf(av[i].x, wv[j].x, acc[i][j]);
        acc[i][j] = fmaf(av[i].y, wv[j].y, acc[i][j]);
        acc[i][j] = fmaf(av[i].z, wv[j].z, acc[i][j]);
        acc[i][j] = fmaf(av[i].w, wv[j].w, acc[i][j]);
      }
  }

  #pragma unroll
  for (int i = 0; i < 8; ++i) {
    const size_t row = r0 + 8 * ty + i;
    *(float4*)(xproj + row * 64 + 8 * tx) =
        make_float4(acc[i][0], acc[i][1], acc[i][2], acc[i][3]);
    *(float4*)(xproj + row * 64 + 8 * tx + 4) =
        make_float4(acc[i][4], acc[i][5], acc[i][6], acc[i][7]);
  }

  // ---- stats (A0 is dead past the half-1 barrier; reuse as scratch)
  float* Sm = (float*)A0;          // [64][33]
  float* Sq = Sm + 64 * 33;
  #pragma unroll
  for (int j = 0; j < 8; ++j) {
    const int col = 8 * tx + j;
    float s = 0.f, q = 0.f;
    #pragma unroll
    for (int i = 0; i < 8; ++i) {  // rows ascending within group
      s += acc[i][j];
      q += acc[i][j] * acc[i][j];
    }
    Sm[col * 33 + ty] = s;
    Sq[col * 33 + ty] = q;
  }
  __syncthreads();
  if (tid < 64) {
    float s0 = 0.f, q0 = 0.f, s1 = 0.f, q1 = 0.f;
    #pragma unroll
    for (int g = 0; g < 16; ++g)  { s0 += Sm[tid * 33 + g]; q0 += Sq[tid * 33 + g]; }
    #pragma unroll
    for (int g = 16; g < 32; ++g) { s1 += Sm[tid * 33 + g]; q1 += Sq[tid * 33 + g]; }
    const size_t p0 = 2 * (size_t)blockIdx.x;
    partials[(size_t)tid * NBLK1 + p0]            = s0;
    partials[(size_t)tid * NBLK1 + p0 + 1]        = s1;
    partials[(size_t)(64 + tid) * NBLK1 + p0]     = q0;
    partials[(size_t)(64 + tid) * NBLK1 + p0 + 1] = q1;
  }
}

// ============ K2a: deterministic f64 reduction (coalesced rows) ============
__global__ __launch_bounds__(256) void k2a_reduce(const float* __restrict__ partials,
                                                  double* __restrict__ statd) {
  __shared__ double sd[256];
  const int idx = blockIdx.x;              // 0..127
  double acc = 0.0;
  for (int k = threadIdx.x; k < NBLK1; k += 256)
    acc += (double)partials[(size_t)idx * NBLK1 + k];
  sd[threadIdx.x] = acc;
  __syncthreads();
  for (int s = 128; s > 0; s >>= 1) {
    if (threadIdx.x < s) sd[threadIdx.x] += sd[threadIdx.x + s];
    __syncthreads();
  }
  if (threadIdx.x == 0) statd[idx] = sd[0];
}

// ============ K2b: BN scale/shift + dynamic thresholds (parallel, 5 blocks) ============
__global__ __launch_bounds__(256) void k2b_final(const double* __restrict__ statd,
                                                 const float* __restrict__ gamma,
                                                 const float* __restrict__ beta,
                                                 const float* __restrict__ tda,
                                                 const float* __restrict__ Wtda,
                                                 const float* __restrict__ btda,
                                                 float* __restrict__ param) {
  const int tid = threadIdx.x, blk = blockIdx.x;
  if (blk == 4) {
    if (tid < 64) {
      double mean = statd[tid] / (double)NROWS;
      double ex2  = statd[64 + tid] / (double)NROWS;
      double var  = ex2 - mean * mean;
      double sc   = (double)gamma[tid] / sqrt(var + 1e-5);
      param[tid]      = (float)sc;
      param[64 + tid] = (float)((double)beta[tid] - mean * sc);
    }
    return;
  }
  const int g = blk * 256 + tid;           // 0..1023 = b*4 + j
  const int b = g >> 2, j = g & 3;
  double acc = (double)btda[j];
  for (int k = 0; k < 50; ++k)
    acc += (double)tda[b * 50 + k] * (double)Wtda[j * 50 + k];
  double sig = 1.0 / (1.0 + exp(-acc));
  param[128 + g] = (float)(1.0 + 0.5 * sig);
}

// ============ K3: layer-1 LIF scan, wave per b, lane = channel h ============
#define K3_LOAD(BUF, TBASE)                         \
  { _Pragma("unroll") for (int i_ = 0; i_ < 64; ++i_) \
      BUF[i_] = xr[(size_t)((TBASE) + i_) * 64]; }

#define K3_CHUNK(CUR, NXT0, TBASE)                                   \
  { unsigned long long keep = 0;                                     \
    _Pragma("unroll") for (int i_ = 0; i_ < 64; ++i_) {              \
      bool sp = (mem >= 1.0f);                                       \
      unsigned long long mb = __ballot(sp);                          \
      if (h == i_) keep = mb;                                        \
      float xrn = (i_ < 63) ? CUR[(i_ + 1) & 63] : (NXT0);           \
      float xn = fmaf(xrn, sc, sh);                                  \
      mem = sp ? xn : fmaf(mem, 0.9f, xn);                           \
    }                                                                \
    masksB[(size_t)b * TB + (TBASE) + h] = keep; }

__global__ __launch_bounds__(64) void k3_scan1(const float* __restrict__ xproj,
                                               const float* __restrict__ param,
                                               unsigned long long* __restrict__ masksB) {
  const int b = blockIdx.x, h = threadIdx.x;
  const float sc = param[h], sh = param[64 + h];
  const float* xr = xproj + (size_t)b * TB * 64 + h;
  float xa[64], xb[64];

  K3_LOAD(xa, 0)
  float mem = fmaf(xa[0], sc, sh);   // t=0 post-add state

  #pragma unroll 1
  for (int t0 = 0; t0 < TB; t0 += 128) {
    K3_LOAD(xb, t0 + 64)
    K3_CHUNK(xa, xb[0], t0)
    if (t0 + 128 < TB) { K3_LOAD(xa, t0 + 128) }
    K3_CHUNK(xb, xa[0], t0 + 64)    // final chunk: trailing xa[0] is dead
  }
}

// ============ K45: fused cur2 (into LDS) + layer-2 LIF scan, block per b ============
#define K45_LOAD(BUF, TBASE)                                             \
  { _Pragma("unroll") for (int k_ = 0; k_ < 16; ++k_) {                  \
      f32x4 v = *(const f32x4*)(cr + (TBASE) + 4 * k_);                  \
      BUF[4 * k_] = v.x; BUF[4 * k_ + 1] = v.y;                          \
      BUF[4 * k_ + 2] = v.z; BUF[4 * k_ + 3] = v.w; } }

#define K45_CHUNK(CUR, NXT0)                                  \
  { _Pragma("unroll") for (int i_ = 0; i_ < 64; ++i_) {       \
      bool sp = (mem >= th);                                  \
      cnt += sp ? 1u : 0u;                                    \
      float xn = (i_ < 63) ? CUR[(i_ + 1) & 63] : (NXT0);     \
      mem = sp ? xn : fmaf(mem, 0.9f, xn);                    \
    } }

__global__ __launch_bounds__(256) void k45_cur2scan(const unsigned long long* __restrict__ masksB,
                                                    const float* __restrict__ Wc,
                                                    const float* __restrict__ lat,
                                                    const float* __restrict__ param,
                                                    float* __restrict__ out) {
  __shared__ float WcL[256];
  __shared__ float latL[16];
  __shared__ float lbuf[4][TB + 4];     // padded rows (stride 2052 floats)
  const int tid = threadIdx.x, b = blockIdx.x;
  WcL[tid] = Wc[tid];
  if (tid < 16) latL[tid] = lat[tid];
  __syncthreads();

  // phase 1: cur2 for all t (identical math to old k4), into LDS
  #pragma unroll 1
  for (int c = 0; c < 8; ++c) {
    const int t = c * 256 + tid;
    const unsigned long long m = masksB[(size_t)b * TB + t];
    const unsigned lo = (unsigned)m, hi = (unsigned)(m >> 32);
    float v0 = 0.f, v1 = 0.f, v2 = 0.f, v3 = 0.f;
    #pragma unroll
    for (int hh = 0; hh < 32; ++hh) {
      const float bit = (float)((lo >> hh) & 1u);
      v0 = fmaf(bit, WcL[hh],       v0);
      v1 = fmaf(bit, WcL[64 + hh],  v1);
      v2 = fmaf(bit, WcL[128 + hh], v2);
      v3 = fmaf(bit, WcL[192 + hh], v3);
    }
    #pragma unroll
    for (int hh = 32; hh < 64; ++hh) {
      const float bit = (float)((hi >> (hh - 32)) & 1u);
      v0 = fmaf(bit, WcL[hh],       v0);
      v1 = fmaf(bit, WcL[64 + hh],  v1);
      v2 = fmaf(bit, WcL[128 + hh], v2);
      v3 = fmaf(bit, WcL[192 + hh], v3);
    }
    { float cx = v0 * latL[0];  cx = fmaf(v1, latL[4],  cx); cx = fmaf(v2, latL[8],  cx); cx = fmaf(v3, latL[12], cx); lbuf[0][t] = cx; }
    { float cx = v0 * latL[1];  cx = fmaf(v1, latL[5],  cx); cx = fmaf(v2, latL[9],  cx); cx = fmaf(v3, latL[13], cx); lbuf[1][t] = cx; }
    { float cx = v0 * latL[2];  cx = fmaf(v1, latL[6],  cx); cx = fmaf(v2, latL[10], cx); cx = fmaf(v3, latL[14], cx); lbuf[2][t] = cx; }
    { float cx = v0 * latL[3];  cx = fmaf(v1, latL[7],  cx); cx = fmaf(v2, latL[11], cx); cx = fmaf(v3, latL[15], cx); lbuf[3][t] = cx; }
  }
  __syncthreads();
  if (tid >= 64) return;

  // phase 2: wave 0 scans from LDS; lanes mirror 4 chains (identical math to old k5)
  const int j4 = tid & 3;
  const float th = param[128 + b * 4 + j4];
  const float* cr = lbuf[j4];
  float ca[64], cb[64];

  K45_LOAD(ca, 0)
  float mem = ca[0];
  unsigned cnt = 0;

  #pragma unroll 1
  for (int t0 = 0; t0 < TB; t0 += 128) {
    K45_LOAD(cb, t0 + 64)
    K45_CHUNK(ca, cb[0])
    if (t0 + 128 < TB) { K45_LOAD(ca, t0 + 128) }
    K45_CHUNK(cb, ca[0])
  }
  if (tid < 4) out[b * 4 + j4] = (float)cnt;
}

extern "C" void kernel_launch(void* const* d_in, const int* in_sizes, int n_in,
                              void* d_out, int out_size, void* d_ws, size_t ws_size,
                              hipStream_t stream) {
  const float* kin   = (const float*)d_in[0];
  const float* tda   = (const float*)d_in[1];
  const float* Wsp   = (const float*)d_in[2];
  const float* gamma = (const float*)d_in[3];
  const float* beta  = (const float*)d_in[4];
  const float* Wc    = (const float*)d_in[5];
  const float* lat   = (const float*)d_in[6];
  const float* Wtda  = (const float*)d_in[7];
  const float* btda  = (const float*)d_in[8];

  char* ws = (char*)d_ws;
  float*  xproj    = (float*)(ws + OFF_X);
  float*  partials = (float*)(ws + OFF_PART);
  double* statd    = (double*)(ws + OFF_STAT);
  float*  param    = (float*)(ws + OFF_PARAM);
  unsigned long long* masksB = (unsigned long long*)(ws + OFF_MASK);
  float*  out      = (float*)d_out;

  k1_gemm  <<<dim3(NBLK_K1), dim3(256), 0, stream>>>(kin, Wsp, xproj, partials);
  k2a_reduce<<<dim3(128),  dim3(256), 0, stream>>>(partials, statd);
  k2b_final<<<dim3(5),     dim3(256), 0, stream>>>(statd, gamma, beta, tda, Wtda, btda, param);
  k3_scan1 <<<dim3(BB),    dim3(64),  0, stream>>>(xproj, param, masksB);
  k45_cur2scan<<<dim3(BB), dim3(256), 0, stream>>>(masksB, Wc, lat, param, out);
}

// Round 9
// 156.808 us; speedup vs baseline: 1.6249x; 1.0091x over previous
//
#include <hip/hip_runtime.h>
#include <cstdint>
#include <cstddef>
#include <cmath>

#define BB 256
#define TB 2048
#define NROWS (BB*TB)          // 524288 rows of [64]
#define R1 256                 // rows per k1 block
#define NBLK_K1 (NROWS/R1)     // 2048 blocks
#define NBLK1 4096             // partial granularity: 128-row groups (bit-compat R5..R8)

typedef float f32x4 __attribute__((ext_vector_type(4)));
typedef float f32x2 __attribute__((ext_vector_type(2)));

// ---- workspace layout (bytes) ----
#define OFF_X      0ull
#define SZ_X       ((size_t)NROWS*64*4)            // 128 MiB raw x_proj [bt][h]
#define OFF_PART   (OFF_X + SZ_X)
#define SZ_PART    ((size_t)128*NBLK1*4)           // 2 MiB partials [ch][4096]
#define OFF_STAT   (OFF_PART + SZ_PART)
#define SZ_STAT    (128*8)                         // f64 col sums / sumsq
#define OFF_MASK   ((OFF_STAT + SZ_STAT + 255ull) & ~255ull)
#define SZ_MASK    ((size_t)NROWS*8)               // 4 MiB spike masks [b][t]

// ============ K1: x_proj = kin @ W^T + 128-row-granular col sum/sumsq ============
// R6's sync LDS staging (proven 80us) + R7's packed pk_fma compute core (proven
// bit-exact). 256 rows x 256 threads, 8x8 tile; per-acc-element c-order = 0..63
// sequential -> bit-identical stats/outputs to R5..R8.
__global__ __launch_bounds__(256, 2) void k1_gemm(const float* __restrict__ kin,
                                                  const float* __restrict__ Wsp,
                                                  float* __restrict__ xproj,
                                                  float* __restrict__ partials) {
  __shared__ float4 As[R1 * 16];   // 64 KB: [r][cc ^ ((r>>3)&7)]
  __shared__ f32x4 Wp[32 * 32];    // 16 KB: [p][q ^ ((p>>2)&7)], pair-interleaved
  const int tid = threadIdx.x;
  const int ty = tid >> 3;         // 0..31 -> rows 8*ty..+7
  const int tx = tid & 7;          // col-pairs p = 4*tx..+3 (cols 8*tx..+7)
  const size_t r0 = (size_t)blockIdx.x * R1;

  // stage A: 4096 float4, 16 per thread, coalesced, nontemporal
  const f32x4* kin4 = (const f32x4*)(kin + r0 * 64);
  #pragma unroll
  for (int k = 0; k < 16; ++k) {
    int idx = k * 256 + tid;
    int r = idx >> 4, cc = idx & 15;
    f32x4 v = __builtin_nontemporal_load(&kin4[idx]);
    As[r * 16 + (cc ^ ((r >> 3) & 7))] = make_float4(v.x, v.y, v.z, v.w);
  }
  // stage W pair-interleaved: (p,q) = {W[2p][2q], W[2p+1][2q], W[2p][2q+1], W[2p+1][2q+1]}
  #pragma unroll
  for (int k = 0; k < 4; ++k) {
    int idx = k * 256 + tid;             // 0..1023
    int p = idx >> 5, q = idx & 31;
    float2 w0 = *(const float2*)(Wsp + (2 * p) * 64 + 2 * q);
    float2 w1 = *(const float2*)(Wsp + (2 * p + 1) * 64 + 2 * q);
    Wp[p * 32 + (q ^ ((p >> 2) & 7))] = (f32x4){w0.x, w1.x, w0.y, w1.y};
  }
  __syncthreads();

  f32x2 acc2[8][4];
  #pragma unroll
  for (int i = 0; i < 8; ++i)
    #pragma unroll
    for (int jp = 0; jp < 4; ++jp) acc2[i][jp] = (f32x2){0.f, 0.f};

  #pragma unroll 1
  for (int cc = 0; cc < 16; ++cc) {
    float4 av[8];
    f32x4 q0[4], q1[4];
    #pragma unroll
    for (int i = 0; i < 8; ++i)
      av[i] = As[(8 * ty + i) * 16 + (cc ^ (ty & 7))];       // (8ty+i)>>3 == ty
    #pragma unroll
    for (int jp = 0; jp < 4; ++jp) {
      const int p = 4 * tx + jp;                              // p>>2 == tx
      q0[jp] = Wp[p * 32 + ((2 * cc)     ^ tx)];              // c = 4cc, 4cc+1
      q1[jp] = Wp[p * 32 + ((2 * cc + 1) ^ tx)];              // c = 4cc+2, 4cc+3
    }
    #pragma unroll
    for (int i = 0; i < 8; ++i) {
      #pragma unroll
      for (int jp = 0; jp < 4; ++jp) {
        // c ascending 4cc..4cc+3 per element -> bit-identical chain to scalar R6
        acc2[i][jp] = __builtin_elementwise_fma((f32x2){av[i].x, av[i].x}, q0[jp].xy, acc2[i][jp]);
        acc2[i][jp] = __builtin_elementwise_fma((f32x2){av[i].y, av[i].y}, q0[jp].zw, acc2[i][jp]);
        acc2[i][jp] = __builtin_elementwise_fma((f32x2){av[i].z, av[i].z}, q1[jp].xy, acc2[i][jp]);
        acc2[i][jp] = __builtin_elementwise_fma((f32x2){av[i].w, av[i].w}, q1[jp].zw, acc2[i][jp]);
      }
    }
  }

  #pragma unroll
  for (int i = 0; i < 8; ++i) {
    const size_t row = r0 + 8 * ty + i;
    f32x4 lo = {acc2[i][0].x, acc2[i][0].y, acc2[i][1].x, acc2[i][1].y};
    f32x4 hi = {acc2[i][2].x, acc2[i][2].y, acc2[i][3].x, acc2[i][3].y};
    *(f32x4*)(xproj + row * 64 + 8 * tx)     = lo;
    *(f32x4*)(xproj + row * 64 + 8 * tx + 4) = hi;
  }

  __syncthreads();                 // As dead; reuse as stat scratch
  float* Sm = (float*)As;          // [64][33]
  float* Sq = Sm + 64 * 33;
  #pragma unroll
  for (int j = 0; j < 8; ++j) {
    const int col = 8 * tx + j;
    float s = 0.f, q = 0.f;
    #pragma unroll
    for (int i = 0; i < 8; ++i) {  // rows ascending within group
      float v = (j & 1) ? acc2[i][j >> 1].y : acc2[i][j >> 1].x;
      s += v;
      q += v * v;
    }
    Sm[col * 33 + ty] = s;
    Sq[col * 33 + ty] = q;
  }
  __syncthreads();
  if (tid < 64) {
    float s0 = 0.f, q0 = 0.f, s1 = 0.f, q1 = 0.f;
    #pragma unroll
    for (int g = 0; g < 16; ++g)  { s0 += Sm[tid * 33 + g]; q0 += Sq[tid * 33 + g]; }
    #pragma unroll
    for (int g = 16; g < 32; ++g) { s1 += Sm[tid * 33 + g]; q1 += Sq[tid * 33 + g]; }
    const size_t p0 = 2 * (size_t)blockIdx.x;
    partials[(size_t)tid * NBLK1 + p0]            = s0;
    partials[(size_t)tid * NBLK1 + p0 + 1]        = s1;
    partials[(size_t)(64 + tid) * NBLK1 + p0]     = q0;
    partials[(size_t)(64 + tid) * NBLK1 + p0 + 1] = q1;
  }
}

// ============ K2a: deterministic f64 reduction (coalesced rows) ============
__global__ __launch_bounds__(256) void k2a_reduce(const float* __restrict__ partials,
                                                  double* __restrict__ statd) {
  __shared__ double sd[256];
  const int idx = blockIdx.x;              // 0..127
  double acc = 0.0;
  for (int k = threadIdx.x; k < NBLK1; k += 256)
    acc += (double)partials[(size_t)idx * NBLK1 + k];
  sd[threadIdx.x] = acc;
  __syncthreads();
  for (int s = 128; s > 0; s >>= 1) {
    if (threadIdx.x < s) sd[threadIdx.x] += sd[threadIdx.x + s];
    __syncthreads();
  }
  if (threadIdx.x == 0) statd[idx] = sd[0];
}

// ============ K3: layer-1 LIF scan; scale/shift derived in-kernel (ex-k2b math) ============
#define K3_LOAD(BUF, TBASE)                         \
  { _Pragma("unroll") for (int i_ = 0; i_ < 64; ++i_) \
      BUF[i_] = xr[(size_t)((TBASE) + i_) * 64]; }

#define K3_CHUNK(CUR, NXT0, TBASE)                                   \
  { unsigned long long keep = 0;                                     \
    _Pragma("unroll") for (int i_ = 0; i_ < 64; ++i_) {              \
      bool sp = (mem >= 1.0f);                                       \
      unsigned long long mb = __ballot(sp);                          \
      if (h == i_) keep = mb;                                        \
      float xrn = (i_ < 63) ? CUR[(i_ + 1) & 63] : (NXT0);           \
      float xn = fmaf(xrn, sc, sh);                                  \
      mem = sp ? xn : fmaf(mem, 0.9f, xn);                           \
    }                                                                \
    masksB[(size_t)b * TB + (TBASE) + h] = keep; }

__global__ __launch_bounds__(64) void k3_scan1(const float* __restrict__ xproj,
                                               const double* __restrict__ statd,
                                               const float* __restrict__ gamma,
                                               const float* __restrict__ beta,
                                               unsigned long long* __restrict__ masksB) {
  const int b = blockIdx.x, h = threadIdx.x;
  // identical expression order to old k2b -> bit-identical sc/sh in every block
  const double mean = statd[h] / (double)NROWS;
  const double ex2  = statd[64 + h] / (double)NROWS;
  const double var  = ex2 - mean * mean;
  const double scd  = (double)gamma[h] / sqrt(var + 1e-5);
  const float sc = (float)scd;
  const float sh = (float)((double)beta[h] - mean * scd);

  const float* xr = xproj + (size_t)b * TB * 64 + h;
  float xa[64], xb[64];

  K3_LOAD(xa, 0)
  float mem = fmaf(xa[0], sc, sh);   // t=0 post-add state

  #pragma unroll 1
  for (int t0 = 0; t0 < TB; t0 += 128) {
    K3_LOAD(xb, t0 + 64)
    K3_CHUNK(xa, xb[0], t0)
    if (t0 + 128 < TB) { K3_LOAD(xa, t0 + 128) }
    K3_CHUNK(xb, xa[0], t0 + 64)    // final chunk: trailing xa[0] is dead
  }
}

// ============ K45: fused cur2 (LDS) + layer-2 scan; thresholds in-kernel ============
#define K45_LOAD(BUF, TBASE)                                             \
  { _Pragma("unroll") for (int k_ = 0; k_ < 16; ++k_) {                  \
      f32x4 v = *(const f32x4*)(cr + (TBASE) + 4 * k_);                  \
      BUF[4 * k_] = v.x; BUF[4 * k_ + 1] = v.y;                          \
      BUF[4 * k_ + 2] = v.z; BUF[4 * k_ + 3] = v.w; } }

#define K45_CHUNK(CUR, NXT0)                                  \
  { _Pragma("unroll") for (int i_ = 0; i_ < 64; ++i_) {       \
      bool sp = (mem >= th);                                  \
      cnt += sp ? 1u : 0u;                                    \
      float xn = (i_ < 63) ? CUR[(i_ + 1) & 63] : (NXT0);     \
      mem = sp ? xn : fmaf(mem, 0.9f, xn);                    \
    } }

__global__ __launch_bounds__(256) void k45_cur2scan(const unsigned long long* __restrict__ masksB,
                                                    const float* __restrict__ Wc,
                                                    const float* __restrict__ lat,
                                                    const float* __restrict__ tda,
                                                    const float* __restrict__ Wtda,
                                                    const float* __restrict__ btda,
                                                    float* __restrict__ out) {
  __shared__ float WcL[256];
  __shared__ float latL[16];
  __shared__ float thL[4];
  __shared__ float lbuf[4][TB + 4];     // padded rows
  const int tid = threadIdx.x, b = blockIdx.x;
  WcL[tid] = Wc[tid];
  if (tid < 16) latL[tid] = lat[tid];
  if (tid >= 32 && tid < 36) {
    // identical expression order to old k2b -> bit-identical thresholds
    const int j = tid - 32;
    double acc = (double)btda[j];
    for (int k = 0; k < 50; ++k)
      acc += (double)tda[b * 50 + k] * (double)Wtda[j * 50 + k];
    double sig = 1.0 / (1.0 + exp(-acc));
    thL[j] = (float)(1.0 + 0.5 * sig);
  }
  __syncthreads();

  // phase 1: cur2 for all t (identical math to old k4), into LDS
  #pragma unroll 1
  for (int c = 0; c < 8; ++c) {
    const int t = c * 256 + tid;
    const unsigned long long m = masksB[(size_t)b * TB + t];
    const unsigned lo = (unsigned)m, hi = (unsigned)(m >> 32);
    float v0 = 0.f, v1 = 0.f, v2 = 0.f, v3 = 0.f;
    #pragma unroll
    for (int hh = 0; hh < 32; ++hh) {
      const float bit = (float)((lo >> hh) & 1u);
      v0 = fmaf(bit, WcL[hh],       v0);
      v1 = fmaf(bit, WcL[64 + hh],  v1);
      v2 = fmaf(bit, WcL[128 + hh], v2);
      v3 = fmaf(bit, WcL[192 + hh], v3);
    }
    #pragma unroll
    for (int hh = 32; hh < 64; ++hh) {
      const float bit = (float)((hi >> (hh - 32)) & 1u);
      v0 = fmaf(bit, WcL[hh],       v0);
      v1 = fmaf(bit, WcL[64 + hh],  v1);
      v2 = fmaf(bit, WcL[128 + hh], v2);
      v3 = fmaf(bit, WcL[192 + hh], v3);
    }
    { float cx = v0 * latL[0];  cx = fmaf(v1, latL[4],  cx); cx = fmaf(v2, latL[8],  cx); cx = fmaf(v3, latL[12], cx); lbuf[0][t] = cx; }
    { float cx = v0 * latL[1];  cx = fmaf(v1, latL[5],  cx); cx = fmaf(v2, latL[9],  cx); cx = fmaf(v3, latL[13], cx); lbuf[1][t] = cx; }
    { float cx = v0 * latL[2];  cx = fmaf(v1, latL[6],  cx); cx = fmaf(v2, latL[10], cx); cx = fmaf(v3, latL[14], cx); lbuf[2][t] = cx; }
    { float cx = v0 * latL[3];  cx = fmaf(v1, latL[7],  cx); cx = fmaf(v2, latL[11], cx); cx = fmaf(v3, latL[15], cx); lbuf[3][t] = cx; }
  }
  __syncthreads();
  if (tid >= 64) return;

  // phase 2: wave 0 scans from LDS; lanes mirror 4 chains (identical math)
  const int j4 = tid & 3;
  const float th = thL[j4];
  const float* cr = lbuf[j4];
  float ca[64], cb[64];

  K45_LOAD(ca, 0)
  float mem = ca[0];
  unsigned cnt = 0;

  #pragma unroll 1
  for (int t0 = 0; t0 < TB; t0 += 128) {
    K45_LOAD(cb, t0 + 64)
    K45_CHUNK(ca, cb[0])
    if (t0 + 128 < TB) { K45_LOAD(ca, t0 + 128) }
    K45_CHUNK(cb, ca[0])
  }
  if (tid < 4) out[b * 4 + j4] = (float)cnt;
}

extern "C" void kernel_launch(void* const* d_in, const int* in_sizes, int n_in,
                              void* d_out, int out_size, void* d_ws, size_t ws_size,
                              hipStream_t stream) {
  const float* kin   = (const float*)d_in[0];
  const float* tda   = (const float*)d_in[1];
  const float* Wsp   = (const float*)d_in[2];
  const float* gamma = (const float*)d_in[3];
  const float* beta  = (const float*)d_in[4];
  const float* Wc    = (const float*)d_in[5];
  const float* lat   = (const float*)d_in[6];
  const float* Wtda  = (const float*)d_in[7];
  const float* btda  = (const float*)d_in[8];

  char* ws = (char*)d_ws;
  float*  xproj    = (float*)(ws + OFF_X);
  float*  partials = (float*)(ws + OFF_PART);
  double* statd    = (double*)(ws + OFF_STAT);
  unsigned long long* masksB = (unsigned long long*)(ws + OFF_MASK);
  float*  out      = (float*)d_out;

  k1_gemm  <<<dim3(NBLK_K1), dim3(256), 0, stream>>>(kin, Wsp, xproj, partials);
  k2a_reduce<<<dim3(128),  dim3(256), 0, stream>>>(partials, statd);
  k3_scan1 <<<dim3(BB),    dim3(64),  0, stream>>>(xproj, statd, gamma, beta, masksB);
  k45_cur2scan<<<dim3(BB), dim3(256), 0, stream>>>(masksB, Wc, lat, tda, Wtda, btda, out);
}